// Round 8
// baseline (182.529 us; speedup 1.0000x reference)
//
#include <hip/hip_runtime.h>
#include <hip/hip_bf16.h>

// AAConv: B=16, C=256, H=W=32, CO=256, DK=DV=128, NH=8, DKH=DVH=16, KS=3
// out ch [0,128) = 3x3 conv (bf16 MFMA), [128,256) = MFMA flash attention.
// R8: prep_x transposes x -> xT[b][hw][c] bf16 once; conv double-buffers LDS
// with 1-load/1-write staging; qkv stages from xT with XOR-swizzled LDS.

#define Bn   16
#define Cin  256
#define HWp  1024
#define COn  256
#define NHn  8

typedef short short8  __attribute__((ext_vector_type(8)));
typedef short short4v __attribute__((ext_vector_type(4)));
typedef float f32x4   __attribute__((ext_vector_type(4)));
typedef float f32x16  __attribute__((ext_vector_type(16)));

__device__ inline short bf16_rne(float f) {
  unsigned u = __builtin_bit_cast(unsigned, f);
  u += 0x7fffu + ((u >> 16) & 1u);
  return (short)(u >> 16);
}

__device__ inline unsigned pkbf(float a, float b) {   // -> v_cvt_pk_bf16_f32
  __hip_bfloat162 h = __float22bfloat162_rn(make_float2(a, b));
  unsigned u;
  __builtin_memcpy(&u, &h, 4);
  return u;
}

__device__ inline void store_bf8(short* dst, const float* f) {
  uint4 u;
  u.x = pkbf(f[0], f[1]); u.y = pkbf(f[2], f[3]);
  u.z = pkbf(f[4], f[5]); u.w = pkbf(f[6], f[7]);
  *(uint4*)dst = u;
}

// ---------------------------------------------------------------------------
// P1: pack ALL weights into bf16 MFMA A-fragments (one launch).
// ---------------------------------------------------------------------------
__global__ __launch_bounds__(256) void prep_all(
    const float* __restrict__ cw, const float* __restrict__ qw,
    const float* __restrict__ pw, short* __restrict__ wfc,
    short* __restrict__ wfq, short* __restrict__ wfp)
{
  const int gid  = blockIdx.x * 256 + threadIdx.x;   // 200*256 = 51200
  const int lane = gid & 63, frag = gid >> 6;        // frag < 800
  const int l15 = lane & 15, q = lane >> 4;
  short8 pk;
  if (frag < 576) {            // conv_w HWIO [9][256][128]
    const int cf = frag & 7, cq = (frag >> 3) & 7, kk = frag >> 6;
    const int co = cf * 16 + l15, c = cq * 32 + q * 8;
#pragma unroll
    for (int j = 0; j < 8; ++j)
      pk[j] = bf16_rne(cw[(size_t)(kk * Cin + c + j) * 128 + co]);
    *(short8*)(wfc + (size_t)frag * 512 + lane * 8) = pk;
  } else if (frag < 768) {     // qkv_w [384][256]
    const int f = frag - 576;
    const int rt = f >> 3, kf = f & 7;
    const int o = rt * 16 + l15, c = kf * 32 + q * 8;
#pragma unroll
    for (int j = 0; j < 8; ++j) pk[j] = bf16_rne(qw[o * Cin + c + j]);
    *(short8*)(wfq + (size_t)f * 512 + lane * 8) = pk;
  } else if (frag < 800) {     // proj_w [128][128]
    const int f = frag - 768;
    const int rt = f >> 2, kf = f & 3;
    const int o = rt * 16 + l15, c = kf * 32 + q * 8;
#pragma unroll
    for (int j = 0; j < 8; ++j) pk[j] = bf16_rne(pw[o * 128 + c + j]);
    *(short8*)(wfp + (size_t)f * 512 + lane * 8) = pk;
  }
}

// ---------------------------------------------------------------------------
// P2: transpose x [b][c][hw] fp32 -> xT [b][hw][c] bf16 via LDS tiles.
// grid 512 blocks (16 b x 8 c-tiles x 4 hw-tiles), 256 threads.
// ---------------------------------------------------------------------------
__global__ __launch_bounds__(256) void prep_x(
    const float* __restrict__ x, short* __restrict__ xt)
{
  __shared__ short t[32][262];          // padded: odd-ish stride, 2-way free
  const int tid = threadIdx.x;
  const int hw0 = (blockIdx.x & 3) * 256;
  const int c0  = ((blockIdx.x >> 2) & 7) * 32;
  const int b   = blockIdx.x >> 5;

#pragma unroll 4
  for (int cc = 0; cc < 32; ++cc)
    t[cc][tid] = bf16_rne(x[(size_t)(b * Cin + c0 + cc) * HWp + hw0 + tid]);
  __syncthreads();

  for (int s = tid; s < 1024; s += 256) {
    const int hwl = s >> 2, q4 = s & 3;
    short8 pk;
#pragma unroll
    for (int j = 0; j < 8; ++j) pk[j] = t[q4 * 8 + j][hwl];
    *(short8*)&xt[((size_t)(b * HWp + hw0 + hwl)) * 256 + c0 + q4 * 8] = pk;
  }
}

// ---------------------------------------------------------------------------
// K2: 3x3 conv implicit GEMM, double-buffered LDS staging from xT.
// 8 waves (512 thr); wave wv owns co-16 tile. grid 256 (16 h-pair x 16 b).
// Staging: slot s = (cell, qq): one 16B load from xT + one ds_write_b128.
// ---------------------------------------------------------------------------
__global__ __launch_bounds__(512) void conv_mfma(
    const short* __restrict__ xt, const short* __restrict__ wf,
    const float* __restrict__ bias, float* __restrict__ out)
{
  __shared__ short xl[2][5712];         // 136 cells * 42 shorts, double buffer
  const int tid  = threadIdx.x;
  const int lane = tid & 63, wv = tid >> 6;      // wv 0..7
  const int l15  = lane & 15, g = lane >> 4;
  const int b  = blockIdx.x >> 4;
  const int h0 = (blockIdx.x & 15) * 2;

  f32x4 acc[4] = {};

#define STAGE(chunk)                                                          \
  {                                                                           \
    const int c0_ = (chunk) * 32;                                             \
    short* dst_ = xl[(chunk) & 1];                                            \
    for (int s = tid; s < 544; s += 512) {                                    \
      const int cell = s >> 2, qq = s & 3;                                    \
      const int r = cell / 34, col = cell - r * 34;                           \
      const int h_in = h0 - 1 + r, w_in = col - 1;                            \
      short8 v = {};                                                          \
      if (h_in >= 0 && h_in < 32 && w_in >= 0 && w_in < 32)                   \
        v = *(const short8*)&xt[((size_t)(b * HWp + h_in * 32 + w_in)) * 256  \
                                + c0_ + qq * 8];                              \
      *(short8*)&dst_[cell * 42 + qq * 8] = v;                                \
    }                                                                         \
  }

  STAGE(0);
  __syncthreads();

  for (int cq = 0; cq < 8; ++cq) {
    if (cq < 7) STAGE(cq + 1);          // issue next chunk (other buffer)
    const short* cur = xl[cq & 1];
#pragma unroll
    for (int kk = 0; kk < 9; ++kk) {
      const int kh = kk / 3, kw = kk - kh * 3;
      const short8 a0 = *(const short8*)(wf + (size_t)((kk * 8 + cq) * 8 + wv) * 512 + lane * 8);
#pragma unroll
      for (int bf = 0; bf < 4; ++bf) {
        const int m = bf * 16 + l15;
        const int r = (m >> 5) + kh, col = (m & 31) + kw;
        const short8 xv = *(const short8*)&cur[(r * 34 + col) * 42 + g * 8];
        acc[bf] = __builtin_amdgcn_mfma_f32_16x16x32_bf16(a0, xv, acc[bf], 0, 0, 0);
      }
    }
    __syncthreads();
  }
#undef STAGE

  const int cob = wv * 16 + g * 4;
#pragma unroll
  for (int r = 0; r < 4; ++r) {
    const int co = cob + r;
    const float bv = bias[co];
    float* op = out + (size_t)(b * COn + co) * HWp + h0 * 32 + l15;
#pragma unroll
    for (int bf = 0; bf < 4; ++bf)
      op[bf * 16] = acc[bf][r] + bv;
  }
}

// ---------------------------------------------------------------------------
// K1: 1x1 QKV conv as MFMA GEMM, staged from xT with XOR-swizzled LDS
// (same bijection on write and read -> conflict-free both sides).
// ---------------------------------------------------------------------------
__global__ __launch_bounds__(512) void qkv_mfma(
    const short* __restrict__ xt, const short* __restrict__ wfq,
    const float* __restrict__ bias, short* __restrict__ qbuf,
    short* __restrict__ kbuf, short* __restrict__ vtbuf)
{
  __shared__ short xl[16384];           // 2048 slots of 16B, swizzled
  const int tid = threadIdx.x, lane = tid & 63, wv = tid >> 6;
  const int l15 = lane & 15, g = lane >> 4;
  const int hw0 = blockIdx.x * 64;
  const int b   = blockIdx.y;

  {
    const int qq = tid & 3, kf = (tid >> 2) & 7, hl = tid >> 5;
#pragma unroll
    for (int mt = 0; mt < 4; ++mt) {
      const int p  = ((mt * 8 + kf) * 4 + qq) * 16 + hl;
      const int sw = p ^ ((p >> 4) & 7);
      const short8 v = *(const short8*)&xt[((size_t)(b * HWp + hw0 + mt * 16 + hl)) * 256
                                           + kf * 32 + qq * 8];
      *(short8*)&xl[sw * 8] = v;
    }
  }
  __syncthreads();

  f32x4 acc[3][4] = {};                 // [rowtile i][mt]
  for (int kf = 0; kf < 8; ++kf) {
    short8 bfr[4];
#pragma unroll
    for (int mt = 0; mt < 4; ++mt) {
      const int q  = ((mt * 8 + kf) * 4 + g) * 16 + l15;
      const int sw = q ^ ((q >> 4) & 7);
      bfr[mt] = *(const short8*)&xl[sw * 8];
    }
#pragma unroll
    for (int i = 0; i < 3; ++i) {
      const int rt = wv * 3 + i;
      const short8 af = *(const short8*)(wfq + ((size_t)(rt * 8 + kf) * 64 + lane) * 8);
#pragma unroll
      for (int mt = 0; mt < 4; ++mt)
        acc[i][mt] = __builtin_amdgcn_mfma_f32_16x16x32_bf16(af, bfr[mt], acc[i][mt], 0, 0, 0);
    }
  }

#pragma unroll
  for (int i = 0; i < 3; ++i) {
    const int rt = wv * 3 + i;          // 0..23
    float bv[4];
#pragma unroll
    for (int r = 0; r < 4; ++r) bv[r] = bias[rt * 16 + 4 * g + r];
    if (rt < 8) {                       // K
      short* kp = kbuf + ((size_t)(b * NHn + rt) * HWp + hw0) * 16 + 4 * g;
#pragma unroll
      for (int mt = 0; mt < 4; ++mt) {
        short4v s;
#pragma unroll
        for (int r = 0; r < 4; ++r) s[r] = bf16_rne(acc[i][mt][r] + bv[r]);
        *(short4v*)(kp + (size_t)(mt * 16 + l15) * 16) = s;
      }
    } else if (rt < 16) {               // Q (x0.25 after bias)
      short* qp = qbuf + ((size_t)(b * NHn + rt - 8) * HWp + hw0) * 16 + 4 * g;
#pragma unroll
      for (int mt = 0; mt < 4; ++mt) {
        short4v s;
#pragma unroll
        for (int r = 0; r < 4; ++r) s[r] = bf16_rne((acc[i][mt][r] + bv[r]) * 0.25f);
        *(short4v*)(qp + (size_t)(mt * 16 + l15) * 16) = s;
      }
    } else {                            // V transposed [bh][d][hw]
      short* vp = vtbuf + (size_t)(b * NHn + rt - 16) * 16 * HWp;
#pragma unroll
      for (int mt = 0; mt < 4; ++mt)
#pragma unroll
        for (int r = 0; r < 4; ++r)
          vp[(size_t)(4 * g + r) * HWp + hw0 + mt * 16 + l15] =
              bf16_rne(acc[i][mt][r] + bv[r]);
    }
  }
}

// ---------------------------------------------------------------------------
// K3: MFMA flash attention v2 (unchanged, verified R7).
// ---------------------------------------------------------------------------
__global__ __launch_bounds__(256) void attn_mfma(
    const short* __restrict__ qb, const short* __restrict__ kb,
    const short* __restrict__ vt, float* __restrict__ abuf)
{
  __shared__ short P[4][2][32][40];     // [wave][buf][q][k] 20.5 KB
  const int tid = threadIdx.x, lane = tid & 63, wv = tid >> 6;
  const int l15 = lane & 15, g = lane >> 4;
  const int l31 = lane & 31, hi = lane >> 5;
  const int h = blockIdx.y, b = blockIdx.z, bh = b * NHn + h;
  const int q0 = blockIdx.x * 128 + wv * 32;

  const short* qp = qb + (size_t)bh * HWp * 16;
  const short* kp = kb + (size_t)bh * HWp * 16;
  const short* vp = vt + (size_t)bh * 16 * HWp;

  // Q B-frag (32x32x16): B[d=hi*8+j][q=l31]
  const short8 qf = *(const short8*)(qp + (size_t)(q0 + l31) * 16 + hi * 8);

  f32x4 o0 = {}, o1 = {};               // O^T: d=4g+r, q = l15 / 16+l15
  float lsum = 0.f;

  for (int kt = 0; kt < HWp; kt += 64) {
#pragma unroll
    for (int t = 0; t < 2; ++t) {
      const int k0 = kt + t * 32;
      const short8 kf = *(const short8*)(kp + (size_t)(k0 + l31) * 16 + hi * 8);
      f32x16 z = {};
      const f32x16 s = __builtin_amdgcn_mfma_f32_32x32x16_bf16(kf, qf, z, 0, 0, 0);
      float p[16];
#pragma unroll
      for (int r = 0; r < 16; ++r) { p[r] = __expf(s[r]); lsum += p[r]; }
#pragma unroll
      for (int rg = 0; rg < 4; ++rg) {
        uint2 u;
        u.x = pkbf(p[4 * rg + 0], p[4 * rg + 1]);
        u.y = pkbf(p[4 * rg + 2], p[4 * rg + 3]);
        *(uint2*)&P[wv][t][l31][8 * rg + 4 * hi] = u;
      }
      const short8 vf = *(const short8*)(vp + (size_t)l15 * HWp + k0 + g * 8);
      const short8 pf0 = *(const short8*)&P[wv][t][l15][g * 8];
      o0 = __builtin_amdgcn_mfma_f32_16x16x32_bf16(vf, pf0, o0, 0, 0, 0);
      const short8 pf1 = *(const short8*)&P[wv][t][16 + l15][g * 8];
      o1 = __builtin_amdgcn_mfma_f32_16x16x32_bf16(vf, pf1, o1, 0, 0, 0);
    }
  }

  const float l  = lsum + __shfl_xor(lsum, 32);    // keyed q=l31
  const float li0 = 1.f / __shfl(l, l15);          // l for q=l15
  const float li1 = 1.f / __shfl(l, 16 + l15);     // l for q=16+l15
#pragma unroll
  for (int r = 0; r < 4; ++r) {
    const int d = 4 * g + r;
    float* op = abuf + (size_t)(b * 128 + h * 16 + d) * HWp + q0;
    op[l15]      = o0[r] * li0;
    op[16 + l15] = o1[r] * li1;
  }
}

// ---------------------------------------------------------------------------
// K4: 1x1 projection as MFMA GEMM (unchanged).
// ---------------------------------------------------------------------------
__global__ __launch_bounds__(256) void proj_mfma(
    const float* __restrict__ a, const short* __restrict__ wfp,
    const float* __restrict__ bias, float* __restrict__ out)
{
  __shared__ short xl[8192];            // [mt4][kf4][q4][l16][j8]
  const int tid = threadIdx.x, lane = tid & 63, wv = tid >> 6;
  const int l15 = lane & 15, g = lane >> 4;
  const int hw0 = blockIdx.x * 64;
  const int b   = blockIdx.y;

#pragma unroll
  for (int it = 0; it < 4; ++it) {
    const int p  = it * 256 + tid;      // 1024 packs
    const int mt = p >> 8, kf = (p >> 6) & 3, qq = (p >> 4) & 3, hl = p & 15;
    const float* ap = a + (size_t)(b * 128 + kf * 32 + qq * 8) * HWp
                        + hw0 + mt * 16 + hl;
    float fv[8];
#pragma unroll
    for (int j = 0; j < 8; ++j) fv[j] = ap[(size_t)j * HWp];
    store_bf8(&xl[p * 8], fv);
  }
  __syncthreads();

  f32x4 acc[2][4] = {};
  for (int kf = 0; kf < 4; ++kf) {
    short8 bfr[4];
#pragma unroll
    for (int mt = 0; mt < 4; ++mt)
      bfr[mt] = *(const short8*)&xl[(((mt * 4 + kf) * 4 + g) * 16 + l15) * 8];
#pragma unroll
    for (int i = 0; i < 2; ++i) {
      const int rt = wv * 2 + i;
      const short8 af = *(const short8*)(wfp + ((size_t)(rt * 4 + kf) * 64 + lane) * 8);
#pragma unroll
      for (int mt = 0; mt < 4; ++mt)
        acc[i][mt] = __builtin_amdgcn_mfma_f32_16x16x32_bf16(af, bfr[mt], acc[i][mt], 0, 0, 0);
    }
  }

#pragma unroll
  for (int i = 0; i < 2; ++i) {
    const int rt = wv * 2 + i;
#pragma unroll
    for (int r = 0; r < 4; ++r) {
      const int o = rt * 16 + 4 * g + r;
      const float bv = bias[o];
      float* op = out + (size_t)(b * COn + 128 + o) * HWp + hw0 + l15;
#pragma unroll
      for (int mt = 0; mt < 4; ++mt)
        op[mt * 16] = acc[i][mt][r] + bv;
    }
  }
}

// ---------------------------------------------------------------------------
extern "C" void kernel_launch(void* const* d_in, const int* in_sizes, int n_in,
                              void* d_out, int out_size, void* d_ws, size_t ws_size,
                              hipStream_t stream) {
  const float* x      = (const float*)d_in[0];
  const float* conv_w = (const float*)d_in[1];
  const float* conv_b = (const float*)d_in[2];
  const float* qkv_w  = (const float*)d_in[3];
  const float* qkv_b  = (const float*)d_in[4];
  const float* proj_w = (const float*)d_in[5];
  const float* proj_b = (const float*)d_in[6];
  float* out = (float*)d_out;

  char* wsb = (char*)d_ws;
  short* wfc    = (short*)wsb;                  // 576 KB conv A-frags
  short* wfq    = (short*)(wsb + (1u << 20));   // 192 KB qkv A-frags
  short* wfp    = (short*)(wsb + (2u << 20));   // 32 KB  proj A-frags
  short* qbuf16 = (short*)(wsb + (8u << 20));   // 4 MB  [bh][hw][16] bf16
  short* kbuf16 = (short*)(wsb + (12u << 20));  // 4 MB  [bh][hw][16] bf16
  short* vtbuf  = (short*)(wsb + (16u << 20));  // 4 MB  [bh][d][hw]  bf16
  float* abuf   = (float*)(wsb + (20u << 20));  // 8 MB  [b][128][hw] fp32
  short* xtbuf  = (short*)(wsb + (28u << 20));  // 8.4 MB [b][hw][c]  bf16

  prep_all  <<<dim3(200), 256, 0, stream>>>(conv_w, qkv_w, proj_w, wfc, wfq, wfp);
  prep_x    <<<dim3(512), 256, 0, stream>>>(x, xtbuf);
  conv_mfma <<<dim3(256), 512, 0, stream>>>(xtbuf, wfc, conv_b, out);
  qkv_mfma  <<<dim3(16, 16), 512, 0, stream>>>(xtbuf, wfq, qkv_b, qbuf16, kbuf16, vtbuf);
  attn_mfma <<<dim3(8, 8, 16), 256, 0, stream>>>(qbuf16, kbuf16, vtbuf, abuf);
  proj_mfma <<<dim3(16, 16), 256, 0, stream>>>(abuf, wfp, proj_b, out);
}

// Round 9
// 169.927 us; speedup vs baseline: 1.0742x; 1.0742x over previous
//
#include <hip/hip_runtime.h>
#include <hip/hip_bf16.h>

// AAConv: B=16, C=256, H=W=32, CO=256, DK=DV=128, NH=8, DKH=DVH=16, KS=3
// out ch [0,128) = 3x3 conv (bf16 MFMA), [128,256) = MFMA flash attention.
// R9: conv = T14 async-stage split (load->regs early, MFMA, write-late) +
// 1-row blocks (grid 512, 2 blocks/CU). prep_all+prep_x merged.

#define Bn   16
#define Cin  256
#define HWp  1024
#define COn  256
#define NHn  8

typedef short short8  __attribute__((ext_vector_type(8)));
typedef short short4v __attribute__((ext_vector_type(4)));
typedef float f32x4   __attribute__((ext_vector_type(4)));
typedef float f32x16  __attribute__((ext_vector_type(16)));

__device__ inline short bf16_rne(float f) {
  unsigned u = __builtin_bit_cast(unsigned, f);
  u += 0x7fffu + ((u >> 16) & 1u);
  return (short)(u >> 16);
}

__device__ inline unsigned pkbf(float a, float b) {   // -> v_cvt_pk_bf16_f32
  __hip_bfloat162 h = __float22bfloat162_rn(make_float2(a, b));
  unsigned u;
  __builtin_memcpy(&u, &h, 4);
  return u;
}

__device__ inline void store_bf8(short* dst, const float* f) {
  uint4 u;
  u.x = pkbf(f[0], f[1]); u.y = pkbf(f[2], f[3]);
  u.z = pkbf(f[4], f[5]); u.w = pkbf(f[6], f[7]);
  *(uint4*)dst = u;
}

// ---------------------------------------------------------------------------
// P1: fused prep. Blocks [0,200): weights -> bf16 A-frags.
// Blocks [200,712): transpose x [b][c][hw] fp32 -> xT [b][hw][c] bf16.
// ---------------------------------------------------------------------------
__global__ __launch_bounds__(256) void prep_fused(
    const float* __restrict__ cw, const float* __restrict__ qw,
    const float* __restrict__ pw, const float* __restrict__ x,
    short* __restrict__ wfc, short* __restrict__ wfq,
    short* __restrict__ wfp, short* __restrict__ xt)
{
  __shared__ short t[32][262];
  const int tid = threadIdx.x;
  if (blockIdx.x < 200) {
    const int gid  = blockIdx.x * 256 + tid;
    const int lane = gid & 63, frag = gid >> 6;      // frag < 800
    const int l15 = lane & 15, q = lane >> 4;
    short8 pk;
    if (frag < 576) {            // conv_w HWIO [9][256][128]
      const int cf = frag & 7, cq = (frag >> 3) & 7, kk = frag >> 6;
      const int co = cf * 16 + l15, c = cq * 32 + q * 8;
#pragma unroll
      for (int j = 0; j < 8; ++j)
        pk[j] = bf16_rne(cw[(size_t)(kk * Cin + c + j) * 128 + co]);
      *(short8*)(wfc + (size_t)frag * 512 + lane * 8) = pk;
    } else if (frag < 768) {     // qkv_w [384][256]
      const int f = frag - 576;
      const int rt = f >> 3, kf = f & 7;
      const int o = rt * 16 + l15, c = kf * 32 + q * 8;
#pragma unroll
      for (int j = 0; j < 8; ++j) pk[j] = bf16_rne(qw[o * Cin + c + j]);
      *(short8*)(wfq + (size_t)f * 512 + lane * 8) = pk;
    } else if (frag < 800) {     // proj_w [128][128]
      const int f = frag - 768;
      const int rt = f >> 2, kf = f & 3;
      const int o = rt * 16 + l15, c = kf * 32 + q * 8;
#pragma unroll
      for (int j = 0; j < 8; ++j) pk[j] = bf16_rne(pw[o * 128 + c + j]);
      *(short8*)(wfp + (size_t)f * 512 + lane * 8) = pk;
    }
  } else {
    const int bid = blockIdx.x - 200;            // 0..511
    const int hw0 = (bid & 3) * 256;
    const int c0  = ((bid >> 2) & 7) * 32;
    const int b   = bid >> 5;
#pragma unroll 4
    for (int cc = 0; cc < 32; ++cc)
      t[cc][tid] = bf16_rne(x[(size_t)(b * Cin + c0 + cc) * HWp + hw0 + tid]);
    __syncthreads();
    for (int s = tid; s < 1024; s += 256) {
      const int hwl = s >> 2, q4 = s & 3;
      short8 pk;
#pragma unroll
      for (int j = 0; j < 8; ++j) pk[j] = t[q4 * 8 + j][hwl];
      *(short8*)&xt[((size_t)(b * HWp + hw0 + hwl)) * 256 + c0 + q4 * 8] = pk;
    }
  }
}

// ---------------------------------------------------------------------------
// K2: 3x3 conv implicit GEMM. One output row (m=32) per block; 4 waves,
// wave wv owns co [wv*32, wv*32+32). grid 512 (32 h x 16 b) -> 2 blocks/CU.
// T14 staging: LOADC (global->reg) | 36 MFMA | WRITEC (drain->LDS) | barrier.
// ---------------------------------------------------------------------------
__global__ __launch_bounds__(256) void conv_mfma(
    const short* __restrict__ xt, const short* __restrict__ wf,
    const float* __restrict__ bias, float* __restrict__ out)
{
  __shared__ short xl[2][102 * 42];     // 3 rows x 34 cols, 42-short cells
  const int tid  = threadIdx.x;
  const int lane = tid & 63, wv = tid >> 6;      // wv 0..3
  const int l15  = lane & 15, g = lane >> 4;
  const int b  = blockIdx.x >> 5;
  const int h0 = blockIdx.x & 31;

  f32x4 acc[2][2] = {};                 // [af][bf]
  short8 rv[2];

#define LOADC(c0_)                                                            \
  {                                                                           \
    _Pragma("unroll")                                                         \
    for (int i = 0; i < 2; ++i) {                                             \
      const int s = tid + i * 256;                                            \
      if (s < 408) {                                                          \
        const int cell = s >> 2, qq = s & 3;                                  \
        const int r = cell / 34, col = cell - r * 34;                         \
        const int h_in = h0 - 1 + r, w_in = col - 1;                          \
        short8 v = {};                                                        \
        if (h_in >= 0 && h_in < 32 && w_in >= 0 && w_in < 32)                 \
          v = *(const short8*)&xt[((size_t)(b * HWp + h_in * 32 + w_in)) * 256\
                                  + (c0_) + qq * 8];                          \
        rv[i] = v;                                                            \
      }                                                                       \
    }                                                                         \
  }
#define WRITEC(bi_)                                                           \
  {                                                                           \
    _Pragma("unroll")                                                         \
    for (int i = 0; i < 2; ++i) {                                             \
      const int s = tid + i * 256;                                            \
      if (s < 408) {                                                          \
        const int cell = s >> 2, qq = s & 3;                                  \
        *(short8*)&xl[bi_][cell * 42 + qq * 8] = rv[i];                       \
      }                                                                       \
    }                                                                         \
  }

  LOADC(0); WRITEC(0);
  __syncthreads();

  for (int cq = 0; cq < 8; ++cq) {
    if (cq < 7) LOADC((cq + 1) * 32);   // loads in flight across the MFMAs
    const short* cur = xl[cq & 1];
#pragma unroll
    for (int kk = 0; kk < 9; ++kk) {
      const int kh = kk / 3, kw = kk - kh * 3;
#pragma unroll
      for (int af = 0; af < 2; ++af) {
        const short8 a0 = *(const short8*)(wf + (size_t)((kk * 8 + cq) * 8 + wv * 2 + af) * 512 + lane * 8);
#pragma unroll
        for (int bf = 0; bf < 2; ++bf) {
          const int m = bf * 16 + l15;
          const short8 xv = *(const short8*)&cur[(kh * 34 + m + kw) * 42 + g * 8];
          acc[af][bf] = __builtin_amdgcn_mfma_f32_16x16x32_bf16(a0, xv, acc[af][bf], 0, 0, 0);
        }
      }
    }
    if (cq < 7) WRITEC((cq + 1) & 1);   // vmcnt drain happens here, post-MFMA
    __syncthreads();
  }
#undef LOADC
#undef WRITEC

#pragma unroll
  for (int af = 0; af < 2; ++af)
#pragma unroll
    for (int r = 0; r < 4; ++r) {
      const int co = (wv * 2 + af) * 16 + 4 * g + r;
      const float bv = bias[co];
      float* op = out + (size_t)(b * COn + co) * HWp + h0 * 32 + l15;
      op[0]  = acc[af][0][r] + bv;
      op[16] = acc[af][1][r] + bv;
    }
}

// ---------------------------------------------------------------------------
// K1: 1x1 QKV conv as MFMA GEMM, staged from xT with XOR-swizzled LDS
// (unchanged from R8).
// ---------------------------------------------------------------------------
__global__ __launch_bounds__(512) void qkv_mfma(
    const short* __restrict__ xt, const short* __restrict__ wfq,
    const float* __restrict__ bias, short* __restrict__ qbuf,
    short* __restrict__ kbuf, short* __restrict__ vtbuf)
{
  __shared__ short xl[16384];           // 2048 slots of 16B, swizzled
  const int tid = threadIdx.x, lane = tid & 63, wv = tid >> 6;
  const int l15 = lane & 15, g = lane >> 4;
  const int hw0 = blockIdx.x * 64;
  const int b   = blockIdx.y;

  {
    const int qq = tid & 3, kf = (tid >> 2) & 7, hl = tid >> 5;
#pragma unroll
    for (int mt = 0; mt < 4; ++mt) {
      const int p  = ((mt * 8 + kf) * 4 + qq) * 16 + hl;
      const int sw = p ^ ((p >> 4) & 7);
      const short8 v = *(const short8*)&xt[((size_t)(b * HWp + hw0 + mt * 16 + hl)) * 256
                                           + kf * 32 + qq * 8];
      *(short8*)&xl[sw * 8] = v;
    }
  }
  __syncthreads();

  f32x4 acc[3][4] = {};                 // [rowtile i][mt]
  for (int kf = 0; kf < 8; ++kf) {
    short8 bfr[4];
#pragma unroll
    for (int mt = 0; mt < 4; ++mt) {
      const int q  = ((mt * 8 + kf) * 4 + g) * 16 + l15;
      const int sw = q ^ ((q >> 4) & 7);
      bfr[mt] = *(const short8*)&xl[sw * 8];
    }
#pragma unroll
    for (int i = 0; i < 3; ++i) {
      const int rt = wv * 3 + i;
      const short8 af = *(const short8*)(wfq + ((size_t)(rt * 8 + kf) * 64 + lane) * 8);
#pragma unroll
      for (int mt = 0; mt < 4; ++mt)
        acc[i][mt] = __builtin_amdgcn_mfma_f32_16x16x32_bf16(af, bfr[mt], acc[i][mt], 0, 0, 0);
    }
  }

#pragma unroll
  for (int i = 0; i < 3; ++i) {
    const int rt = wv * 3 + i;          // 0..23
    float bv[4];
#pragma unroll
    for (int r = 0; r < 4; ++r) bv[r] = bias[rt * 16 + 4 * g + r];
    if (rt < 8) {                       // K
      short* kp = kbuf + ((size_t)(b * NHn + rt) * HWp + hw0) * 16 + 4 * g;
#pragma unroll
      for (int mt = 0; mt < 4; ++mt) {
        short4v s;
#pragma unroll
        for (int r = 0; r < 4; ++r) s[r] = bf16_rne(acc[i][mt][r] + bv[r]);
        *(short4v*)(kp + (size_t)(mt * 16 + l15) * 16) = s;
      }
    } else if (rt < 16) {               // Q (x0.25 after bias)
      short* qp = qbuf + ((size_t)(b * NHn + rt - 8) * HWp + hw0) * 16 + 4 * g;
#pragma unroll
      for (int mt = 0; mt < 4; ++mt) {
        short4v s;
#pragma unroll
        for (int r = 0; r < 4; ++r) s[r] = bf16_rne((acc[i][mt][r] + bv[r]) * 0.25f);
        *(short4v*)(qp + (size_t)(mt * 16 + l15) * 16) = s;
      }
    } else {                            // V transposed [bh][d][hw]
      short* vp = vtbuf + (size_t)(b * NHn + rt - 16) * 16 * HWp;
#pragma unroll
      for (int mt = 0; mt < 4; ++mt)
#pragma unroll
        for (int r = 0; r < 4; ++r)
          vp[(size_t)(4 * g + r) * HWp + hw0 + mt * 16 + l15] =
              bf16_rne(acc[i][mt][r] + bv[r]);
    }
  }
}

// ---------------------------------------------------------------------------
// K3: MFMA flash attention v2 (unchanged, verified R7).
// ---------------------------------------------------------------------------
__global__ __launch_bounds__(256) void attn_mfma(
    const short* __restrict__ qb, const short* __restrict__ kb,
    const short* __restrict__ vt, float* __restrict__ abuf)
{
  __shared__ short P[4][2][32][40];     // [wave][buf][q][k] 20.5 KB
  const int tid = threadIdx.x, lane = tid & 63, wv = tid >> 6;
  const int l15 = lane & 15, g = lane >> 4;
  const int l31 = lane & 31, hi = lane >> 5;
  const int h = blockIdx.y, b = blockIdx.z, bh = b * NHn + h;
  const int q0 = blockIdx.x * 128 + wv * 32;

  const short* qp = qb + (size_t)bh * HWp * 16;
  const short* kp = kb + (size_t)bh * HWp * 16;
  const short* vp = vt + (size_t)bh * 16 * HWp;

  // Q B-frag (32x32x16): B[d=hi*8+j][q=l31]
  const short8 qf = *(const short8*)(qp + (size_t)(q0 + l31) * 16 + hi * 8);

  f32x4 o0 = {}, o1 = {};               // O^T: d=4g+r, q = l15 / 16+l15
  float lsum = 0.f;

  for (int kt = 0; kt < HWp; kt += 64) {
#pragma unroll
    for (int t = 0; t < 2; ++t) {
      const int k0 = kt + t * 32;
      const short8 kf = *(const short8*)(kp + (size_t)(k0 + l31) * 16 + hi * 8);
      f32x16 z = {};
      const f32x16 s = __builtin_amdgcn_mfma_f32_32x32x16_bf16(kf, qf, z, 0, 0, 0);
      float p[16];
#pragma unroll
      for (int r = 0; r < 16; ++r) { p[r] = __expf(s[r]); lsum += p[r]; }
#pragma unroll
      for (int rg = 0; rg < 4; ++rg) {
        uint2 u;
        u.x = pkbf(p[4 * rg + 0], p[4 * rg + 1]);
        u.y = pkbf(p[4 * rg + 2], p[4 * rg + 3]);
        *(uint2*)&P[wv][t][l31][8 * rg + 4 * hi] = u;
      }
      const short8 vf = *(const short8*)(vp + (size_t)l15 * HWp + k0 + g * 8);
      const short8 pf0 = *(const short8*)&P[wv][t][l15][g * 8];
      o0 = __builtin_amdgcn_mfma_f32_16x16x32_bf16(vf, pf0, o0, 0, 0, 0);
      const short8 pf1 = *(const short8*)&P[wv][t][16 + l15][g * 8];
      o1 = __builtin_amdgcn_mfma_f32_16x16x32_bf16(vf, pf1, o1, 0, 0, 0);
    }
  }

  const float l  = lsum + __shfl_xor(lsum, 32);    // keyed q=l31
  const float li0 = 1.f / __shfl(l, l15);          // l for q=l15
  const float li1 = 1.f / __shfl(l, 16 + l15);     // l for q=16+l15
#pragma unroll
  for (int r = 0; r < 4; ++r) {
    const int d = 4 * g + r;
    float* op = abuf + (size_t)(b * 128 + h * 16 + d) * HWp + q0;
    op[l15]      = o0[r] * li0;
    op[16 + l15] = o1[r] * li1;
  }
}

// ---------------------------------------------------------------------------
// K4: 1x1 projection as MFMA GEMM (unchanged).
// ---------------------------------------------------------------------------
__global__ __launch_bounds__(256) void proj_mfma(
    const float* __restrict__ a, const short* __restrict__ wfp,
    const float* __restrict__ bias, float* __restrict__ out)
{
  __shared__ short xl[8192];            // [mt4][kf4][q4][l16][j8]
  const int tid = threadIdx.x, lane = tid & 63, wv = tid >> 6;
  const int l15 = lane & 15, g = lane >> 4;
  const int hw0 = blockIdx.x * 64;
  const int b   = blockIdx.y;

#pragma unroll
  for (int it = 0; it < 4; ++it) {
    const int p  = it * 256 + tid;      // 1024 packs
    const int mt = p >> 8, kf = (p >> 6) & 3, qq = (p >> 4) & 3, hl = p & 15;
    const float* ap = a + (size_t)(b * 128 + kf * 32 + qq * 8) * HWp
                        + hw0 + mt * 16 + hl;
    float fv[8];
#pragma unroll
    for (int j = 0; j < 8; ++j) fv[j] = ap[(size_t)j * HWp];
    store_bf8(&xl[p * 8], fv);
  }
  __syncthreads();

  f32x4 acc[2][4] = {};
  for (int kf = 0; kf < 4; ++kf) {
    short8 bfr[4];
#pragma unroll
    for (int mt = 0; mt < 4; ++mt)
      bfr[mt] = *(const short8*)&xl[(((mt * 4 + kf) * 4 + g) * 16 + l15) * 8];
#pragma unroll
    for (int i = 0; i < 2; ++i) {
      const int rt = wv * 2 + i;
      const short8 af = *(const short8*)(wfp + ((size_t)(rt * 4 + kf) * 64 + lane) * 8);
#pragma unroll
      for (int mt = 0; mt < 4; ++mt)
        acc[i][mt] = __builtin_amdgcn_mfma_f32_16x16x32_bf16(af, bfr[mt], acc[i][mt], 0, 0, 0);
    }
  }

#pragma unroll
  for (int i = 0; i < 2; ++i) {
    const int rt = wv * 2 + i;
#pragma unroll
    for (int r = 0; r < 4; ++r) {
      const int o = rt * 16 + 4 * g + r;
      const float bv = bias[o];
      float* op = out + (size_t)(b * COn + 128 + o) * HWp + hw0 + l15;
#pragma unroll
      for (int mt = 0; mt < 4; ++mt)
        op[mt * 16] = acc[i][mt][r] + bv;
    }
  }
}

// ---------------------------------------------------------------------------
extern "C" void kernel_launch(void* const* d_in, const int* in_sizes, int n_in,
                              void* d_out, int out_size, void* d_ws, size_t ws_size,
                              hipStream_t stream) {
  const float* x      = (const float*)d_in[0];
  const float* conv_w = (const float*)d_in[1];
  const float* conv_b = (const float*)d_in[2];
  const float* qkv_w  = (const float*)d_in[3];
  const float* qkv_b  = (const float*)d_in[4];
  const float* proj_w = (const float*)d_in[5];
  const float* proj_b = (const float*)d_in[6];
  float* out = (float*)d_out;

  char* wsb = (char*)d_ws;
  short* wfc    = (short*)wsb;                  // 576 KB conv A-frags
  short* wfq    = (short*)(wsb + (1u << 20));   // 192 KB qkv A-frags
  short* wfp    = (short*)(wsb + (2u << 20));   // 32 KB  proj A-frags
  short* qbuf16 = (short*)(wsb + (8u << 20));   // 4 MB  [bh][hw][16] bf16
  short* kbuf16 = (short*)(wsb + (12u << 20));  // 4 MB  [bh][hw][16] bf16
  short* vtbuf  = (short*)(wsb + (16u << 20));  // 4 MB  [bh][d][hw]  bf16
  float* abuf   = (float*)(wsb + (20u << 20));  // 8 MB  [b][128][hw] fp32
  short* xtbuf  = (short*)(wsb + (28u << 20));  // 8.4 MB [b][hw][c]  bf16

  prep_fused<<<dim3(712), 256, 0, stream>>>(conv_w, qkv_w, proj_w, x,
                                            wfc, wfq, wfp, xtbuf);
  conv_mfma <<<dim3(512), 256, 0, stream>>>(xtbuf, wfc, conv_b, out);
  qkv_mfma  <<<dim3(16, 16), 512, 0, stream>>>(xtbuf, wfq, qkv_b, qbuf16, kbuf16, vtbuf);
  attn_mfma <<<dim3(8, 8, 16), 256, 0, stream>>>(qbuf16, kbuf16, vtbuf, abuf);
  proj_mfma <<<dim3(16, 16), 256, 0, stream>>>(abuf, wfp, proj_b, out);
}